// Round 1
// baseline (537.603 us; speedup 1.0000x reference)
//
#include <hip/hip_runtime.h>

// KPConv fused kernel, fp32 vector-ALU version (round 1: correctness + sane structure).
// Q=20000 queries, H=32 neighbors, K=15 kernel pts, C=128 in, O=128 out.
// Stage A: f[q,k,c] = sum_h relu(1-|n_qh - q - kp_k|) * feat[n_qh, c]   (in LDS)
// Stage B: out[q,o] = sum_{k,c} f[q,k,c] * W[k,c,o]
// QB=16 queries per 256-thread block -> f_lds = 16*1920*4 = 120 KB LDS, 1 block/CU.

constexpr int Qn = 20000;
constexpr int Hn = 32;
constexpr int Kn = 15;
constexpr int Cn = 128;
constexpr int On = 128;
constexpr int QB = 16;
constexpr int ROWS = Kn * Cn; // 1920
constexpr int BLOCK = 256;

__global__ __launch_bounds__(BLOCK, 1)
void kpconv_fused(const float* __restrict__ qpts,
                  const float* __restrict__ sfeat,
                  const float* __restrict__ kpts,
                  const float* __restrict__ wts,
                  const int* __restrict__ nidx,
                  float* __restrict__ out) {
  __shared__ float f_lds[QB][ROWS];       // 120 KB
  __shared__ float infl[2][Hn][16];       // 4 KB (k padded 15->16, [15]=0)
  __shared__ int   nl[2 * Hn];            // 256 B
  __shared__ float qp_l[6];               // 2 query points

  const int t = threadIdx.x;
  const int qbase = blockIdx.x * QB;

  // ---------------- Phase A: build f[q][k*128+c] in LDS, 2 queries at a time
  for (int p = 0; p < QB / 2; ++p) {
    const int q0 = qbase + 2 * p;
    if (t < 64) nl[t] = nidx[q0 * Hn + t];          // 2 queries x 32 neighbors
    if (t < 6)  qp_l[t] = qpts[q0 * 3 + t];
    if (t >= 64 && t < 128) infl[(t - 64) >> 5][(t - 64) & 31][15] = 0.f;
    __syncthreads();

    // influences: 2*32*15 = 960 items
    for (int idx = t; idx < 2 * Hn * Kn; idx += BLOCK) {
      int qp  = idx / (Hn * Kn);
      int rem = idx - qp * (Hn * Kn);
      int h   = rem / Kn;
      int k   = rem - h * Kn;
      int g   = nl[qp * Hn + h];
      // NOTE: reference gathers neighbor POINTS from query_points (not support_points)
      float dx = qpts[g * 3 + 0] - qp_l[qp * 3 + 0] - kpts[k * 3 + 0];
      float dy = qpts[g * 3 + 1] - qp_l[qp * 3 + 1] - kpts[k * 3 + 1];
      float dz = qpts[g * 3 + 2] - qp_l[qp * 3 + 2] - kpts[k * 3 + 2];
      float d  = sqrtf(dx * dx + dy * dy + dz * dz);
      infl[qp][h][k] = fmaxf(0.f, 1.f - d);
    }
    __syncthreads();

    // f accumulation: thread -> (c = t&127, qp = t>>7)
    const int c  = t & 127;
    const int qp = t >> 7;
    float facc[16];
#pragma unroll
    for (int i = 0; i < 16; ++i) facc[i] = 0.f;

#pragma unroll 4
    for (int h = 0; h < Hn; ++h) {
      int g = nl[qp * Hn + h];
      float feat = sfeat[g * Cn + c];   // coalesced 512B row gather (L2/LLC hit)
      const float4* ip = (const float4*)&infl[qp][h][0];
      float4 i0 = ip[0], i1 = ip[1], i2 = ip[2], i3 = ip[3];
      facc[0]  += i0.x * feat; facc[1]  += i0.y * feat;
      facc[2]  += i0.z * feat; facc[3]  += i0.w * feat;
      facc[4]  += i1.x * feat; facc[5]  += i1.y * feat;
      facc[6]  += i1.z * feat; facc[7]  += i1.w * feat;
      facc[8]  += i2.x * feat; facc[9]  += i2.y * feat;
      facc[10] += i2.z * feat; facc[11] += i2.w * feat;
      facc[12] += i3.x * feat; facc[13] += i3.y * feat;
      facc[14] += i3.z * feat; // facc[15] is the pad lane, ignored
    }
    const int qi = 2 * p + qp;
#pragma unroll
    for (int k = 0; k < Kn; ++k) f_lds[qi][k * Cn + c] = facc[k];
    __syncthreads();
  }

  // ---------------- Phase B: out[q][o] = sum_row f[q][row] * W[row][o]
  // thread -> 4 consecutive o (og..og+3), row-eighth rr
  const int og = (t & 31) * 4;
  const int rr = t >> 5;   // 0..7
  float acc[QB][4];
#pragma unroll
  for (int q = 0; q < QB; ++q) {
    acc[q][0] = 0.f; acc[q][1] = 0.f; acc[q][2] = 0.f; acc[q][3] = 0.f;
  }

  for (int base = 0; base < ROWS; base += 8) {
    int row = base + rr;
    float4 w4 = *(const float4*)&wts[row * On + og];
#pragma unroll
    for (int q = 0; q < QB; ++q) {
      float fv = f_lds[q][row];   // wave-broadcast ds_read_b32
      acc[q][0] += fv * w4.x;
      acc[q][1] += fv * w4.y;
      acc[q][2] += fv * w4.z;
      acc[q][3] += fv * w4.w;
    }
  }
  __syncthreads();   // done reading f_lds; reuse it as reduction scratch

  float* red = &f_lds[0][0];   // [QB][8][128] = 64 KB
#pragma unroll
  for (int q = 0; q < QB; ++q) {
    float4* rp = (float4*)&red[(q * 8 + rr) * 128 + og];
    *rp = make_float4(acc[q][0], acc[q][1], acc[q][2], acc[q][3]);
  }
  __syncthreads();

  // final 8-way rr reduction + store: thread -> (q = t>>4, 8 consecutive o)
  {
    const int q  = t >> 4;
    const int ob = (t & 15) * 8;
    float s[8];
#pragma unroll
    for (int j = 0; j < 8; ++j) s[j] = 0.f;
#pragma unroll
    for (int r = 0; r < 8; ++r) {
      const float4* rp = (const float4*)&red[(q * 8 + r) * 128 + ob];
      float4 a = rp[0], b = rp[1];
      s[0] += a.x; s[1] += a.y; s[2] += a.z; s[3] += a.w;
      s[4] += b.x; s[5] += b.y; s[6] += b.z; s[7] += b.w;
    }
    float4* op = (float4*)&out[(qbase + q) * On + ob];
    op[0] = make_float4(s[0], s[1], s[2], s[3]);
    op[1] = make_float4(s[4], s[5], s[6], s[7]);
  }
}

extern "C" void kernel_launch(void* const* d_in, const int* in_sizes, int n_in,
                              void* d_out, int out_size, void* d_ws, size_t ws_size,
                              hipStream_t stream) {
  const float* qpts  = (const float*)d_in[0];  // query_points   [Q,3]
  // d_in[1] = support_points (unused by the reference math)
  const float* sfeat = (const float*)d_in[2];  // support_features [G,C]
  const float* kpts  = (const float*)d_in[3];  // kernel         [K,3]
  const float* wts   = (const float*)d_in[4];  // weights        [K,C,O]
  const int*   nidx  = (const int*)d_in[5];    // neighbor_indices [Q,H]
  float* out = (float*)d_out;

  dim3 grid(Qn / QB);   // 20000/16 = 1250
  kpconv_fused<<<grid, BLOCK, 0, stream>>>(qpts, sfeat, kpts, wts, nidx, out);
}

// Round 2
// 227.967 us; speedup vs baseline: 2.3583x; 2.3583x over previous
//
#include <hip/hip_runtime.h>

// KPConv round 2: bf16 MFMA phase B + sparsity-skipped phase A + 2 blocks/CU.
// Q=20000, H=32, K=15, C=128, O=128.
// Phase A (VALU fp32, skip empty (q,h)): f[q,k,c] = sum_h relu(1-d)*feat  -> LDS bf16 (swizzled)
// Phase B (MFMA 16x16x32 bf16): out[16q x 128o] = f[16 x 1920] @ W[1920 x 128]
// W pre-converted per launch into B-fragment order in d_ws.

typedef short bf16x8 __attribute__((ext_vector_type(8)));
typedef float f32x4 __attribute__((ext_vector_type(4)));

constexpr int Qn = 20000;
constexpr int Hn = 32;
constexpr int Kn = 15;
constexpr int Cn = 128;
constexpr int On = 128;
constexpr int QB = 16;
constexpr int ROWS = Kn * Cn;   // 1920
constexpr int KT = ROWS / 32;   // 60 K-tiles
constexpr int NT = On / 16;     // 8 N-tiles
constexpr int BLOCK = 256;

// LDS pool byte offsets (total 80448 <= 81920 -> 2 blocks/CU)
constexpr int F_OFF    = 0;                  // bf16 f[16][1920], XOR-swizzled rows (61440 B)
constexpr int INFL_OFF = 61440;              // bf16 infl[16][32][16] (16384 B)
constexpr int NIDX_OFF = INFL_OFF + 16384;   // int  nidx[16][32]    (2048 B)
constexpr int QP_OFF   = NIDX_OFF + 2048;    // f32  qp[16][4]       (256 B)
constexpr int KP_OFF   = QP_OFF + 256;       // f32  kp[16][4]       (256 B, 15 used)
constexpr int FLG_OFF  = KP_OFF + 256;       // u32  flags[16]       (64 B)
constexpr int POOL_SZ  = FLG_OFF + 64;       // 80448
// npt f32[16][32][4] (8192 B) aliases F_OFF during influence build (f not yet written)

__device__ __forceinline__ unsigned short f2bf(float x) {  // RNE
  unsigned u = __float_as_uint(x);
  unsigned r = u + 0x7fffu + ((u >> 16) & 1u);
  return (unsigned short)(r >> 16);
}
__device__ __forceinline__ float bflo(unsigned u) { return __uint_as_float(u << 16); }
__device__ __forceinline__ float bfhi(unsigned u) { return __uint_as_float(u & 0xffff0000u); }

// ---------------- W -> bf16 B-fragment layout: wfrag[kt][nt][lane][j(8)]
// lane l of a wave holds B[k = kt*32 + (l>>4)*8 + j][n = nt*16 + (l&15)]
__global__ void conv_w(const float* __restrict__ wts, unsigned short* __restrict__ wfrag) {
  int tid = blockIdx.x * 256 + threadIdx.x;
  if (tid >= KT * NT * 64) return;
  int l = tid & 63, nt = (tid >> 6) & 7, kt = tid >> 9;
  int col = nt * 16 + (l & 15);
  int r0 = kt * 32 + (l >> 4) * 8;
  unsigned short v[8];
#pragma unroll
  for (int j = 0; j < 8; ++j) v[j] = f2bf(wts[(r0 + j) * On + col]);
  uint4 o;
  o.x = (unsigned)v[0] | ((unsigned)v[1] << 16);
  o.y = (unsigned)v[2] | ((unsigned)v[3] << 16);
  o.z = (unsigned)v[4] | ((unsigned)v[5] << 16);
  o.w = (unsigned)v[6] | ((unsigned)v[7] << 16);
  *(uint4*)(wfrag + (size_t)tid * 8) = o;
}

__global__ __launch_bounds__(BLOCK, 2)
void kpconv_main(const float* __restrict__ qpts,
                 const float* __restrict__ sfeat,
                 const float* __restrict__ kpts,
                 const int* __restrict__ nidx,
                 const unsigned short* __restrict__ wfrag,
                 float* __restrict__ out) {
  __shared__ __align__(16) char pool[POOL_SZ];
  unsigned short* infl = (unsigned short*)(pool + INFL_OFF);
  int*      nidxl = (int*)(pool + NIDX_OFF);
  float*    qpl   = (float*)(pool + QP_OFF);
  float*    kpl   = (float*)(pool + KP_OFF);
  unsigned* flg   = (unsigned*)(pool + FLG_OFF);
  float*    npt   = (float*)pool;   // alias over F region during build

  const int t = threadIdx.x;
  const int qbase = blockIdx.x * QB;

  // ---- stage indices, neighbor points, query points, kernel points
  if (t < 16) {
    flg[t] = 0;
    qpl[t * 4 + 0] = qpts[(qbase + t) * 3 + 0];
    qpl[t * 4 + 1] = qpts[(qbase + t) * 3 + 1];
    qpl[t * 4 + 2] = qpts[(qbase + t) * 3 + 2];
  } else if (t >= 16 && t < 16 + Kn) {
    int k = t - 16;
    kpl[k * 4 + 0] = kpts[k * 3 + 0];
    kpl[k * 4 + 1] = kpts[k * 3 + 1];
    kpl[k * 4 + 2] = kpts[k * 3 + 2];
  }
  for (int idx = t; idx < QB * Hn; idx += BLOCK) {   // idx = q*32 + h
    int g = nidx[(size_t)qbase * Hn + idx];
    nidxl[idx] = g;
    npt[idx * 4 + 0] = qpts[g * 3 + 0];   // reference gathers from query_points
    npt[idx * 4 + 1] = qpts[g * 3 + 1];
    npt[idx * 4 + 2] = qpts[g * 3 + 2];
  }
  __syncthreads();

  // ---- influences (bf16) + per-(q,h) nonzero flags
  for (int idx = t; idx < QB * Hn * 16; idx += BLOCK) {  // [q][h][k], k padded to 16
    int k = idx & 15, h = (idx >> 4) & 31, q = idx >> 9;
    unsigned short v = 0;
    if (k < Kn) {
      float dx = npt[(q * 32 + h) * 4 + 0] - qpl[q * 4 + 0] - kpl[k * 4 + 0];
      float dy = npt[(q * 32 + h) * 4 + 1] - qpl[q * 4 + 1] - kpl[k * 4 + 1];
      float dz = npt[(q * 32 + h) * 4 + 2] - qpl[q * 4 + 2] - kpl[k * 4 + 2];
      float d = sqrtf(dx * dx + dy * dy + dz * dz);
      float inf = fmaxf(0.f, 1.f - d);
      if (inf > 0.f) atomicOr(&flg[q], 1u << h);
      v = f2bf(inf);
    }
    infl[idx] = v;
  }
  __syncthreads();   // npt dead from here; F region writable

  // ---- phase A: f[q][k*128+c] (bf16, swizzled), skipping empty (q,h)
  {
    const int c = t & 127;
    const int qh = t >> 7;   // waves 0,1 -> queries 0..7; waves 2,3 -> 8..15
    for (int i = 0; i < 8; ++i) {
      const int q = qh * 8 + i;
      unsigned m = flg[q];   // wave-uniform
      float facc[15];
#pragma unroll
      for (int k = 0; k < 15; ++k) facc[k] = 0.f;
      while (m) {
        int h = __ffs(m) - 1; m &= m - 1;
        int g = nidxl[q * 32 + h];
        float feat = sfeat[(size_t)g * Cn + c];   // coalesced 256B/wave gather
        const uint4* ip = (const uint4*)(infl + (q * 32 + h) * 16);
        uint4 A = ip[0], B = ip[1];               // broadcast ds_read_b128 x2
        facc[0]  += bflo(A.x) * feat; facc[1]  += bfhi(A.x) * feat;
        facc[2]  += bflo(A.y) * feat; facc[3]  += bfhi(A.y) * feat;
        facc[4]  += bflo(A.z) * feat; facc[5]  += bfhi(A.z) * feat;
        facc[6]  += bflo(A.w) * feat; facc[7]  += bfhi(A.w) * feat;
        facc[8]  += bflo(B.x) * feat; facc[9]  += bfhi(B.x) * feat;
        facc[10] += bflo(B.y) * feat; facc[11] += bfhi(B.y) * feat;
        facc[12] += bflo(B.z) * feat; facc[13] += bfhi(B.z) * feat;
        facc[14] += bflo(B.w) * feat;
      }
      const unsigned rb = (unsigned)q * (ROWS * 2);
      const unsigned sw = ((unsigned)q & 7u) << 4;
#pragma unroll
      for (int k = 0; k < 15; ++k) {
        unsigned byte = (rb + (unsigned)(k * Cn + c) * 2u) ^ sw;
        *(unsigned short*)(pool + byte) = f2bf(facc[k]);
      }
    }
  }
  __syncthreads();

  // ---- phase B: MFMA 16x16x32 bf16. wave w -> N-tiles {2w, 2w+1}
  {
    const int l = t & 63, w = t >> 6;
    const int nt0 = w * 2, nt1 = nt0 + 1;
    const int arow = l & 15;            // q row for A-fragment
    const unsigned kgoff = (unsigned)(l >> 4) * 16u;   // bytes within K-tile
    const unsigned abase = (unsigned)arow * (ROWS * 2);
    const unsigned aswz = ((unsigned)arow & 7u) << 4;
    const uint4* wf = (const uint4*)wfrag;

    f32x4 acc0 = {0.f, 0.f, 0.f, 0.f}, acc1 = {0.f, 0.f, 0.f, 0.f};
    bf16x8 aA, aB; uint4 b0A, b1A, b0B, b1B;

#define LOADA(kt) { aA = *(const bf16x8*)(pool + ((abase + (unsigned)(kt) * 64u + kgoff) ^ aswz)); \
                    b0A = wf[((kt) * NT + nt0) * 64 + l]; b1A = wf[((kt) * NT + nt1) * 64 + l]; }
#define LOADB(kt) { aB = *(const bf16x8*)(pool + ((abase + (unsigned)(kt) * 64u + kgoff) ^ aswz)); \
                    b0B = wf[((kt) * NT + nt0) * 64 + l]; b1B = wf[((kt) * NT + nt1) * 64 + l]; }

    LOADA(0); LOADB(1);
#pragma unroll
    for (int kt = 0; kt < KT; kt += 2) {
      { bf16x8 bb0 = *(bf16x8*)&b0A, bb1 = *(bf16x8*)&b1A;
        acc0 = __builtin_amdgcn_mfma_f32_16x16x32_bf16(aA, bb0, acc0, 0, 0, 0);
        acc1 = __builtin_amdgcn_mfma_f32_16x16x32_bf16(aA, bb1, acc1, 0, 0, 0); }
      if (kt + 2 < KT) LOADA(kt + 2);
      { bf16x8 bb0 = *(bf16x8*)&b0B, bb1 = *(bf16x8*)&b1B;
        acc0 = __builtin_amdgcn_mfma_f32_16x16x32_bf16(aB, bb0, acc0, 0, 0, 0);
        acc1 = __builtin_amdgcn_mfma_f32_16x16x32_bf16(aB, bb1, acc1, 0, 0, 0); }
      if (kt + 3 < KT) LOADB(kt + 3);
    }
#undef LOADA
#undef LOADB

    // C/D layout: col = lane&15, row = (lane>>4)*4 + r
    const int orow = (l >> 4) * 4;
    const int ocol = l & 15;
    float* obase = out + (size_t)qbase * On;
#pragma unroll
    for (int r = 0; r < 4; ++r) {
      obase[(orow + r) * On + nt0 * 16 + ocol] = acc0[r];
      obase[(orow + r) * On + nt1 * 16 + ocol] = acc1[r];
    }
  }
}

extern "C" void kernel_launch(void* const* d_in, const int* in_sizes, int n_in,
                              void* d_out, int out_size, void* d_ws, size_t ws_size,
                              hipStream_t stream) {
  const float* qpts  = (const float*)d_in[0];  // query_points [Q,3]
  const float* sfeat = (const float*)d_in[2];  // support_features [G,C]
  const float* kpts  = (const float*)d_in[3];  // kernel [K,3]
  const float* wts   = (const float*)d_in[4];  // weights [K,C,O]
  const int*   nidx  = (const int*)d_in[5];    // neighbor_indices [Q,H]
  float* outp = (float*)d_out;
  unsigned short* wfrag = (unsigned short*)d_ws;   // 491520 B needed

  conv_w<<<(KT * NT * 64 + 255) / 256, 256, 0, stream>>>(wts, wfrag);
  kpconv_main<<<Qn / QB, BLOCK, 0, stream>>>(qpts, sfeat, kpts, nidx, wfrag, outp);
}

// Round 4
// 190.277 us; speedup vs baseline: 2.8254x; 1.1981x over previous
//
#include <hip/hip_runtime.h>

// KPConv round 3 (resubmit after broker timeout): BOTH phases on MFMA.
// Phase A per query q: f[k(16), c(128)] = infl[k(16), slot(32)] @ feat[slot(32), c(128)]
//   - one 16x16x32 bf16 MFMA per (q, c-tile); neighbor slots compacted (avg ~6/32 active)
//   - feat B-fragments gathered per-lane directly from global (predicated), no LDS staging
// f stored in LDS k-fastest: ck = c*16 + k (2048-dim contraction, k=15 pad rows = 0)
//   - phase-A D writes = contiguous ds_write_b64 (conflict-free)
//   - phase-B A reads = ds_read_b128, XOR-swizzled on q (2-way)
// Phase B: out[16q x 128o] = f[16 x 2048] @ W'[2048 x 128], W' pre-converted to
// B-fragment order (k-fastest rows) in d_ws by conv_w.

typedef short bf16x8 __attribute__((ext_vector_type(8)));
typedef float f32x4 __attribute__((ext_vector_type(4)));

constexpr int Qn = 20000;
constexpr int Hn = 32;
constexpr int Kn = 15;
constexpr int Cn = 128;
constexpr int On = 128;
constexpr int QB = 16;
constexpr int CK = 2048;        // contraction dim: c*16 + k (k padded to 16)
constexpr int KT = CK / 32;     // 64 K-tiles
constexpr int NT = On / 16;     // 8 N-tiles
constexpr int BLOCK = 512;      // 8 waves

// LDS pool (bytes)
constexpr int F_OFF     = 0;        // bf16 f[16][2048], swizzle ^((q&7)<<4)        65536
constexpr int NPT_OFF   = 0;        // alias: f32 npt[16][32][4] (dead before f)     8192
constexpr int DENSE_OFF = 8192;     // alias: bf16 dense[16][32][16] (dead before f) 16384
constexpr int INFL_OFF  = 65536;    // bf16 infl_s[16][16k][32slot], swz ^((k&7)<<4) 16384
constexpr int GLIST_OFF = 81920;    // int  glist[16][32]                             2048
constexpr int NIDX_OFF  = 83968;    // int  nidxl[16][32]                             2048
constexpr int HLIST_OFF = 86016;    // i16  hlist[16][32]                             1024
constexpr int CNT_OFF   = 87040;    // int  count[16]                                   64
constexpr int QPL_OFF   = 87104;    // f32  qpl[16][4]                                 256
constexpr int KPL_OFF   = 87360;    // f32  kpl[16][4]                                 256
constexpr int FLG_OFF   = 87616;    // u32  flg[16]                                     64
constexpr int POOL_SZ   = 87680;

__device__ __forceinline__ unsigned short f2bf(float x) {  // RNE
  unsigned u = __float_as_uint(x);
  unsigned r = u + 0x7fffu + ((u >> 16) & 1u);
  return (unsigned short)(r >> 16);
}

// ---- W -> bf16 B-fragment layout, k-fastest rows: wfrag[kt][nt][lane][j(8)]
// lane l holds W'[ck = kt*32 + (l>>4)*8 + j][o = nt*16 + (l&15)], ck = c*16+k
__global__ void conv_w(const float* __restrict__ wts, unsigned short* __restrict__ wfrag) {
  int tid = blockIdx.x * 256 + threadIdx.x;
  if (tid >= KT * NT * 64) return;
  int l = tid & 63, nt = (tid >> 6) & 7, kt = tid >> 9;
  int col = nt * 16 + (l & 15);
  int ck0 = kt * 32 + (l >> 4) * 8;
  unsigned short v[8];
#pragma unroll
  for (int j = 0; j < 8; ++j) {
    int ck = ck0 + j;
    int k = ck & 15, c = ck >> 4;
    v[j] = (k < Kn) ? f2bf(wts[(k * Cn + c) * On + col]) : (unsigned short)0;
  }
  uint4 o;
  o.x = (unsigned)v[0] | ((unsigned)v[1] << 16);
  o.y = (unsigned)v[2] | ((unsigned)v[3] << 16);
  o.z = (unsigned)v[4] | ((unsigned)v[5] << 16);
  o.w = (unsigned)v[6] | ((unsigned)v[7] << 16);
  *(uint4*)(wfrag + (size_t)tid * 8) = o;
}

__global__ __launch_bounds__(BLOCK, 1)
void kpconv_main(const float* __restrict__ qpts,
                 const float* __restrict__ sfeat,
                 const float* __restrict__ kpts,
                 const int* __restrict__ nidx,
                 const unsigned short* __restrict__ wfrag,
                 float* __restrict__ out) {
  __shared__ __align__(16) char pool[POOL_SZ];
  const int t = threadIdx.x;
  const int qbase = blockIdx.x * QB;
  const int l = t & 63, w = t >> 6;       // wave id 0..7
  const int lg = l >> 4, li = l & 15;

  // ---------------- P0: stage points/indices, zero infl_s
  {
    int g = nidx[(size_t)qbase * Hn + t];             // t = q*32+h
    *(int*)(pool + NIDX_OFF + t * 4) = g;
    float* np = (float*)(pool + NPT_OFF + t * 16);
    np[0] = qpts[g * 3 + 0];
    np[1] = qpts[g * 3 + 1];
    np[2] = qpts[g * 3 + 2];
    uint4 z = {0, 0, 0, 0};
    *(uint4*)(pool + INFL_OFF + t * 32) = z;
    *(uint4*)(pool + INFL_OFF + t * 32 + 16) = z;
    if (t < 16) {
      *(unsigned*)(pool + FLG_OFF + t * 4) = 0u;
      float* qp = (float*)(pool + QPL_OFF + t * 16);
      qp[0] = qpts[(qbase + t) * 3 + 0];
      qp[1] = qpts[(qbase + t) * 3 + 1];
      qp[2] = qpts[(qbase + t) * 3 + 2];
    }
    if (t >= 32 && t < 32 + Kn) {
      int k = t - 32;
      float* kp = (float*)(pool + KPL_OFF + k * 16);
      kp[0] = kpts[k * 3 + 0];
      kp[1] = kpts[k * 3 + 1];
      kp[2] = kpts[k * 3 + 2];
    }
  }
  __syncthreads();

  // ---------------- P1: dense influences -> dense buf + activity flags
#pragma unroll
  for (int it = 0; it < 16; ++it) {
    int idx = t + it * BLOCK;              // [q][h][k16]
    int k = idx & 15, h = (idx >> 4) & 31, q = idx >> 9;
    unsigned short v = 0;
    if (k < Kn) {
      const float* np = (const float*)(pool + NPT_OFF + (q * 32 + h) * 16);
      const float* qp = (const float*)(pool + QPL_OFF + q * 16);
      const float* kp = (const float*)(pool + KPL_OFF + k * 16);
      float dx = np[0] - qp[0] - kp[0];
      float dy = np[1] - qp[1] - kp[1];
      float dz = np[2] - qp[2] - kp[2];
      float d = sqrtf(dx * dx + dy * dy + dz * dz);
      float inf = fmaxf(0.f, 1.f - d);
      if (inf > 0.f) atomicOr((unsigned*)(pool + FLG_OFF) + q, 1u << h);
      v = f2bf(inf);
    }
    *(unsigned short*)(pool + DENSE_OFF + q * 1024 + h * 32 + k * 2) = v;
  }
  __syncthreads();

  // ---------------- P2: compact active-h lists
  if (t < 16) {
    unsigned m = *(unsigned*)(pool + FLG_OFF + t * 4);
    int cnt = __popc(m);
    *(int*)(pool + CNT_OFF + t * 4) = cnt;
    int i = 0;
    while (m) {
      int h = __ffs(m) - 1; m &= m - 1;
      *(short*)(pool + HLIST_OFF + t * 64 + i * 2) = (short)h;
      *(int*)(pool + GLIST_OFF + t * 128 + i * 4) = *(int*)(pool + NIDX_OFF + (t * 32 + h) * 4);
      ++i;
    }
  }
  __syncthreads();

  // ---------------- P3: scatter influences into A-frag layout infl_s[q][k][slot]
#pragma unroll
  for (int it = 0; it < 16; ++it) {
    int idx = t + it * BLOCK;              // [q][k16][slot32]
    int slot = idx & 31, k = (idx >> 5) & 15, q = idx >> 9;
    int cnt = *(const int*)(pool + CNT_OFF + q * 4);
    if (k < Kn && slot < cnt) {
      int h = *(const short*)(pool + HLIST_OFF + q * 64 + slot * 2);
      unsigned short v = *(const unsigned short*)(pool + DENSE_OFF + q * 1024 + h * 32 + k * 2);
      unsigned byte = (unsigned)(q * 1024) + (((unsigned)(k * 64 + slot * 2)) ^ (((unsigned)k & 7u) << 4));
      *(unsigned short*)(pool + INFL_OFF + byte) = v;
    }
  }
  __syncthreads();   // npt/dense dead from here; f region free

  // ---------------- P4: phase-A MFMA. wave w -> c-tile w, all 16 q
  {
    const unsigned abase0 = (unsigned)INFL_OFF +
        (((unsigned)(li * 64 + lg * 16)) ^ (((unsigned)li & 7u) << 4));
    const int cbase = w * 16 + li;         // c column this lane produces/consumes
    for (int q = 0; q < QB; ++q) {
      bf16x8 afrag = *(const bf16x8*)(pool + abase0 + q * 1024);
      uint4 ga = *(const uint4*)(pool + GLIST_OFF + q * 128 + lg * 32);
      uint4 gb = *(const uint4*)(pool + GLIST_OFF + q * 128 + lg * 32 + 16);
      int cnt = *(const int*)(pool + CNT_OFF + q * 4);
      int s0 = lg * 8;
      float v0 = (s0 + 0 < cnt) ? sfeat[(size_t)ga.x * Cn + cbase] : 0.f;
      float v1 = (s0 + 1 < cnt) ? sfeat[(size_t)ga.y * Cn + cbase] : 0.f;
      float v2 = (s0 + 2 < cnt) ? sfeat[(size_t)ga.z * Cn + cbase] : 0.f;
      float v3 = (s0 + 3 < cnt) ? sfeat[(size_t)ga.w * Cn + cbase] : 0.f;
      float v4 = (s0 + 4 < cnt) ? sfeat[(size_t)gb.x * Cn + cbase] : 0.f;
      float v5 = (s0 + 5 < cnt) ? sfeat[(size_t)gb.y * Cn + cbase] : 0.f;
      float v6 = (s0 + 6 < cnt) ? sfeat[(size_t)gb.z * Cn + cbase] : 0.f;
      float v7 = (s0 + 7 < cnt) ? sfeat[(size_t)gb.w * Cn + cbase] : 0.f;
      uint4 bu;
      bu.x = (unsigned)f2bf(v0) | ((unsigned)f2bf(v1) << 16);
      bu.y = (unsigned)f2bf(v2) | ((unsigned)f2bf(v3) << 16);
      bu.z = (unsigned)f2bf(v4) | ((unsigned)f2bf(v5) << 16);
      bu.w = (unsigned)f2bf(v6) | ((unsigned)f2bf(v7) << 16);
      bf16x8 bfrag = *(bf16x8*)&bu;
      f32x4 zero = {0.f, 0.f, 0.f, 0.f};
      f32x4 d = __builtin_amdgcn_mfma_f32_16x16x32_bf16(afrag, bfrag, zero, 0, 0, 0);
      // D: row k = lg*4 + r, col c = cbase -> f[q][c*16 + k], 4 consecutive shorts
      unsigned wb = ((unsigned)(cbase * 32 + lg * 8) ^ (((unsigned)q & 7u) << 4)) + (unsigned)(q * 4096);
      uint2 pk;
      pk.x = (unsigned)f2bf(d[0]) | ((unsigned)f2bf(d[1]) << 16);
      pk.y = (unsigned)f2bf(d[2]) | ((unsigned)f2bf(d[3]) << 16);
      *(uint2*)(pool + F_OFF + wb) = pk;
    }
  }
  __syncthreads();

  // ---------------- P5: phase-B MFMA. wave w -> N-tile w
  {
    const int nt = w;
    const unsigned fb = (unsigned)(li * 4096 + lg * 16);
    const unsigned fswz = ((unsigned)li & 7u) << 4;
    const uint4* wf = (const uint4*)wfrag + (size_t)nt * 64 + l;
    f32x4 acc0 = {0.f, 0.f, 0.f, 0.f}, acc1 = {0.f, 0.f, 0.f, 0.f};
#pragma unroll 8
    for (int kt = 0; kt < KT; kt += 2) {
      bf16x8 a0 = *(const bf16x8*)(pool + F_OFF + ((fb + (unsigned)(kt * 64)) ^ fswz));
      uint4 w0 = wf[(size_t)kt * 512];
      bf16x8 a1 = *(const bf16x8*)(pool + F_OFF + ((fb + (unsigned)(kt * 64 + 64)) ^ fswz));
      uint4 w1 = wf[(size_t)kt * 512 + 512];
      acc0 = __builtin_amdgcn_mfma_f32_16x16x32_bf16(a0, *(bf16x8*)&w0, acc0, 0, 0, 0);
      acc1 = __builtin_amdgcn_mfma_f32_16x16x32_bf16(a1, *(bf16x8*)&w1, acc1, 0, 0, 0);
    }
    f32x4 acc = acc0 + acc1;
    // D: row q = lg*4 + r, col o = nt*16 + li
    float* obase = out + (size_t)qbase * On;
#pragma unroll
    for (int r = 0; r < 4; ++r)
      obase[(lg * 4 + r) * On + nt * 16 + li] = acc[r];
  }
}

extern "C" void kernel_launch(void* const* d_in, const int* in_sizes, int n_in,
                              void* d_out, int out_size, void* d_ws, size_t ws_size,
                              hipStream_t stream) {
  const float* qpts  = (const float*)d_in[0];  // query_points [Q,3]
  const float* sfeat = (const float*)d_in[2];  // support_features [G,C]
  const float* kpts  = (const float*)d_in[3];  // kernel [K,3]
  const float* wts   = (const float*)d_in[4];  // weights [K,C,O]
  const int*   nidx  = (const int*)d_in[5];    // neighbor_indices [Q,H]
  float* outp = (float*)d_out;
  unsigned short* wfrag = (unsigned short*)d_ws;   // 524288 B needed

  conv_w<<<(KT * NT * 64 + 255) / 256, 256, 0, stream>>>(wts, wfrag);
  kpconv_main<<<Qn / QB, BLOCK, 0, stream>>>(qpts, sfeat, kpts, nidx, wfrag, outp);
}